// Round 3
// baseline (70.914 us; speedup 1.0000x reference)
//
#include <hip/hip_runtime.h>
#include <cfloat>

typedef short bf16x8 __attribute__((ext_vector_type(8)));
typedef float f32x4  __attribute__((ext_vector_type(4)));

static __device__ __forceinline__ void gl_lds16(const void* g, void* l) {
    __builtin_amdgcn_global_load_lds(
        (const __attribute__((address_space(1))) unsigned int*)g,
        (__attribute__((address_space(3))) unsigned int*)l, 16, 0, 0);
}

static __device__ __forceinline__ unsigned int pack2(float a, float b) {
    unsigned short ha = __builtin_bit_cast(unsigned short, (__bf16)a);
    unsigned short hb = __builtin_bit_cast(unsigned short, (__bf16)b);
    return (unsigned int)ha | ((unsigned int)hb << 16);
}

// ---------------- kernel 1: prep ----------------
// blocks 0..63   : W -> bf16 pre-swizzled wh + ||w||^2 ; block 0 zeroes accumulators
// blocks 64..191 : X -> token-major bf16 pre-swizzled Xt + ||x||^2 (zero LDS:
//                  lane = token = fast axis of NCHW, 256B/instr coalesced)
__global__ __launch_bounds__(256) void prep_kernel(
    const float* __restrict__ W, const float* __restrict__ X,
    unsigned short* __restrict__ wh, float* __restrict__ cw,
    unsigned short* __restrict__ xt, float* __restrict__ xnorm,
    float* __restrict__ lossAcc, unsigned int* __restrict__ counter)
{
    int t = threadIdx.x, blk = blockIdx.x;
    if (blk < 64) {
        int row = blk * 16 + (t >> 4);
        int c0  = (t & 15) * 16;
        const float* wr = W + row * 256 + c0;
        float s = 0.f;
        unsigned int pk[8];
#pragma unroll
        for (int i = 0; i < 16; i += 2) {
            float a = wr[i], b = wr[i + 1];
            s += a * a + b * b;
            pk[i >> 1] = pack2(a, b);
        }
        int g0 = (t & 15) * 2, e = row & 7;
        uint4* dst = (uint4*)&wh[row * 256];
        dst[g0 ^ e]       = make_uint4(pk[0], pk[1], pk[2], pk[3]);
        dst[(g0 + 1) ^ e] = make_uint4(pk[4], pk[5], pk[6], pk[7]);
#pragma unroll
        for (int m = 1; m < 16; m <<= 1) s += __shfl_xor(s, m, 64);
        if ((t & 15) == 0) cw[row] = s;
        if (blk == 0 && t == 0) { *lossAcc = 0.f; *counter = 0u; }
    } else {
        int tok = (blk - 64) * 256 + t;            // lanes = consecutive tokens
        int b = tok >> 10, s = tok & 1023;
        const float* xp = X + ((size_t)b << 18) + s;
        float acc = 0.f;
        int e = tok & 7;
        uint4* dst = (uint4*)&xt[(size_t)tok * 256];
#pragma unroll
        for (int g = 0; g < 32; ++g) {
            unsigned int pk[4];
#pragma unroll
            for (int p = 0; p < 4; ++p) {
                float a = xp[(size_t)(g * 8 + p * 2)     << 10];
                float c = xp[(size_t)(g * 8 + p * 2 + 1) << 10];
                acc = fmaf(a, a, fmaf(c, c, acc));
                pk[p] = pack2(a, c);
            }
            dst[g ^ e] = make_uint4(pk[0], pk[1], pk[2], pk[3]);
        }
        xnorm[tok] = acc;
    }
}

// ---------------- kernel 2: W-stationary distance-GEMM + per-quarter argmin ----
// grid 256 = 64 token-groups x 4 code-quarters; block 512thr (8 waves), 1/CU.
// W quarter (256 codes, 128KB bf16) resident in LDS, loaded once via
// global_load_lds (linear: wh is pre-swizzled). Wave = 64 tokens, X fragments
// in registers (direct dwordx4 from pre-swizzled Xt). Barrier-free main loop.
__global__ __launch_bounds__(512, 2) void argmin_kernel(
    const unsigned short* __restrict__ wh, const unsigned short* __restrict__ xt,
    const float* __restrict__ cw, float2* __restrict__ partial)
{
    __shared__ unsigned short wlds[256 * 256];     // 128 KB
    int tid  = threadIdx.x;
    int lane = tid & 63, w = tid >> 6;
    int g = blockIdx.x >> 2, q = blockIdx.x & 3;
    int srow = lane & 15, kgrp = lane >> 4;

    // stage W quarter: wave w owns rows [w*32, w*32+32)  (16 x 1KB DMA)
    const char* wsrc = (const char*)wh + (size_t)(q * 256 + w * 32) * 512;
    char* wdst = (char*)wlds + w * 16384;
#pragma unroll
    for (int j = 0; j < 16; ++j)
        gl_lds16(wsrc + j * 1024 + lane * 16, wdst + j * 1024);

    // X fragments (overlap with W DMA)
    int T0 = g * 512 + w * 64;
    bf16x8 fx[4][8];
#pragma unroll
    for (int tt = 0; tt < 4; ++tt) {
        int T = T0 + tt * 16 + srow, e = T & 7;
        const unsigned short* xr = xt + (size_t)T * 256;
#pragma unroll
        for (int ks = 0; ks < 8; ++ks)
            fx[tt][ks] = *(const bf16x8*)&xr[((ks * 4 + kgrp) ^ e) * 8];
    }
    asm volatile("s_waitcnt vmcnt(0)" ::: "memory");
    __syncthreads();                               // W quarter visible to all waves

    float best[4] = {FLT_MAX, FLT_MAX, FLT_MAX, FLT_MAX};
    int   bidx[4] = {0, 0, 0, 0};
    const float* cwq = cw + q * 256;

    for (int ch = 0; ch < 16; ++ch) {
        int r = ch * 16 + srow, eb = r & 7;
        const unsigned short* ar = &wlds[r * 256];
        bf16x8 af[8];
#pragma unroll
        for (int ks = 0; ks < 8; ++ks)
            af[ks] = *(const bf16x8*)&ar[((ks * 4 + kgrp) ^ eb) * 8];

        float4 cw4 = *(const float4*)&cwq[ch * 16 + kgrp * 4];

        f32x4 acc[4];
#pragma unroll
        for (int tt = 0; tt < 4; ++tt) acc[tt] = (f32x4){0.f, 0.f, 0.f, 0.f};
#pragma unroll
        for (int ks = 0; ks < 8; ++ks)
#pragma unroll
            for (int tt = 0; tt < 4; ++tt)
                acc[tt] = __builtin_amdgcn_mfma_f32_16x16x32_bf16(
                    af[ks], fx[tt][ks], acc[tt], 0, 0, 0);

        int cb = q * 256 + ch * 16 + kgrp * 4;
#pragma unroll
        for (int j = 0; j < 4; ++j) {
            float cwv = j == 0 ? cw4.x : j == 1 ? cw4.y : j == 2 ? cw4.z : cw4.w;
#pragma unroll
            for (int tt = 0; tt < 4; ++tt) {
                float e2 = fmaf(-2.f, acc[tt][j], cwv);
                bool better = e2 < best[tt];       // strict <: lowest code wins
                best[tt] = better ? e2 : best[tt];
                bidx[tt] = better ? (cb + j) : bidx[tt];
            }
        }
    }

    // in-wave argmin over kgrp groups, then per-quarter partial to global
#pragma unroll
    for (int tt = 0; tt < 4; ++tt) {
        float v = best[tt]; int id = bidx[tt];
#pragma unroll
        for (int m = 16; m <= 32; m <<= 1) {
            float ve = __shfl_xor(v, m, 64);
            int   ie = __shfl_xor(id, m, 64);
            if (ve < v || (ve == v && ie < id)) { v = ve; id = ie; }
        }
        if (lane < 16)
            partial[(size_t)q * 32768 + T0 + tt * 16 + lane] =
                make_float2(v, __int_as_float(id));
    }
}

// ---------------- kernel 3: combine quarters + gather + NCHW store + losses ----
__global__ __launch_bounds__(256) void out_kernel(
    const float* __restrict__ W, const float2* __restrict__ partial,
    const float* __restrict__ xnorm, float* __restrict__ lossAcc,
    unsigned int* __restrict__ counter, float* __restrict__ out)
{
    __shared__ float tile[256][65];
    __shared__ int lidx[64];
    int t = threadIdx.x, g = blockIdx.x;
    int n0 = g * 64;
    int b = n0 >> 10, sb = n0 & 1023;

    if (t < 64) {
        float2 p = partial[n0 + t];
        float v = p.x; int id = __float_as_int(p.y);
#pragma unroll
        for (int q = 1; q < 4; ++q) {
            float2 pq = partial[(size_t)q * 32768 + n0 + t];
            if (pq.x < v) { v = pq.x; id = __float_as_int(pq.y); }  // tie -> lower q
        }
        lidx[t] = id;
        float dmin = xnorm[n0 + t] + v;
#pragma unroll
        for (int m = 1; m < 64; m <<= 1) dmin += __shfl_xor(dmin, m, 64);
        if (t == 0) {
            atomicAdd(lossAcc, dmin);
            __threadfence();
            if (atomicAdd(counter, 1u) == 511u) {   // last block writes losses
                __threadfence();
                float tot = atomicAdd(lossAcc, 0.f);
                float mse = tot * (1.0f / 8388608.0f);
                out[8388608] = 1.25f * mse;         // vq_loss
                out[8388609] = mse;                 // embedding_loss
                out[8388610] = mse;                 // commitment_loss
            }
        }
    }
    __syncthreads();

    int tok = t >> 2, cq = t & 3;
    const float* wr = W + ((size_t)lidx[tok] << 8);
#pragma unroll
    for (int j = 0; j < 16; ++j) {
        int c = cq * 4 + j * 16;
        float4 v = *(const float4*)&wr[c];
        tile[c + 0][tok] = v.x; tile[c + 1][tok] = v.y;
        tile[c + 2][tok] = v.z; tile[c + 3][tok] = v.w;
    }
    __syncthreads();
    float* op = out + (((size_t)(b * 256 + t)) << 10) + sb;
#pragma unroll
    for (int j = 0; j < 16; ++j) {
        float4 v;
        v.x = tile[t][j * 4 + 0]; v.y = tile[t][j * 4 + 1];
        v.z = tile[t][j * 4 + 2]; v.w = tile[t][j * 4 + 3];
        *(float4*)&op[j * 4] = v;
    }
}

extern "C" void kernel_launch(void* const* d_in, const int* in_sizes, int n_in,
                              void* d_out, int out_size, void* d_ws, size_t ws_size,
                              hipStream_t stream)
{
    (void)in_sizes; (void)n_in; (void)out_size; (void)ws_size;
    const float* X = (const float*)d_in[0];   // [32,256,32,32] fp32
    const float* W = (const float*)d_in[1];   // [1024,256] fp32
    float* out = (float*)d_out;               // [8388608 out | vq | emb | commit]
    char* ws = (char*)d_ws;
    float*          lossAcc = (float*)ws;                       // @0
    unsigned int*   counter = (unsigned int*)(ws + 8);          // @8
    float*          cw      = (float*)(ws + 4096);              // 4KB
    unsigned short* wh      = (unsigned short*)(ws + 8192);     // 512KB (swizzled bf16)
    float*          xnorm   = (float*)(ws + 1048576);           // 128KB
    unsigned short* xt      = (unsigned short*)(ws + 2097152);  // 16.8MB (swizzled bf16)
    float2*         partial = (float2*)(ws + 19922944);         // 1MB

    prep_kernel<<<192, 256, 0, stream>>>(W, X, wh, cw, xt, xnorm, lossAcc, counter);
    argmin_kernel<<<256, 512, 0, stream>>>(wh, xt, cw, partial);
    out_kernel<<<512, 256, 0, stream>>>(W, partial, xnorm, lossAcc, counter, out);
}